// Round 7
// baseline (201.031 us; speedup 1.0000x reference)
//
#include <hip/hip_runtime.h>

// VectorQuantizer R16: fused full-K gemm+finalize; one-time LDS A; B streamed.
//   wh = f16(16*w_hat), wl = f16(16*w_hat - wh)   (uniform x16: argmax-invariant)
//   zh = f16(4*z),      zl = f16(4*z - zh)        (uniform x4:  argmax-invariant)
//   dot = hh + hl + lh  (single f32 accumulator chain; ll ~2^-22 rel, dropped)
// argmin_k ||z_hat - w_hat_k|| == argmax_k <z, w_hat_k>  -> only codebook normalized.
//
// R9-R15 record: three gemm structures all 70-83us @ MfmaUtil 25-29%; per-kt
// barrier/drain cycle (LDS variants) or load-use collapse (reg variants) is
// the invariant cost, AND total-gemm ~= 80-94us of prep/finalize/overhead.
// R16: block = 64 px x ALL 1024 codes (grid 512 = 2/CU, tail-free).
//  - A (64KB h+l) DMA'd to LDS ONCE; K-loop has ZERO barriers -> 8 waves/CU
//    free-run and destagger (TLP covers B's L2 latency).
//  - B (1MB, L2-resident) streamed direct to regs, all blocks in same order.
//  - argmax completes in-block -> finalize epilogue fused (w_n gather ->
//    LDS tile -> coalesced zq stores); kernel 3 + cand traffic deleted.

typedef _Float16 half8 __attribute__((ext_vector_type(8)));
typedef float    floatx4 __attribute__((ext_vector_type(4)));

#define C_DIM 256
#define K_CODES 1024
#define HW 1024
#define NPIX 32768

#define GLOAD_LDS16(g, l) __builtin_amdgcn_global_load_lds(                    \
    (const __attribute__((address_space(1))) unsigned int*)(g),                \
    (__attribute__((address_space(3))) unsigned int*)(l), 16, 0, 0)

// ---------------- kernel 1: norm codebook  +  z transpose/split -------------
// (unchanged from R14/R15, verified twice)
__global__ __launch_bounds__(256) void vq_prep(
        const float* __restrict__ z, const float* __restrict__ w,
        float* __restrict__ w_n, _Float16* __restrict__ wfh, _Float16* __restrict__ wfl,
        _Float16* __restrict__ zfh, _Float16* __restrict__ zfl) {
    __shared__ float wsum[4];
    __shared__ unsigned pk[64][257];   // h | l<<16 ; stride 257: 2-way-free writes
    const int t = threadIdx.x;

    if (blockIdx.x < K_CODES) {
        const int c = blockIdx.x;          // code row
        float x = w[c * C_DIM + t];
        float s = x * x;
        #pragma unroll
        for (int off = 32; off > 0; off >>= 1) s += __shfl_down(s, off, 64);
        if ((t & 63) == 0) wsum[t >> 6] = s;
        __syncthreads();
        float tot = wsum[0] + wsum[1] + wsum[2] + wsum[3];
        float inv = 1.0f / fmaxf(sqrtf(tot), 1e-12f);
        float y = x * inv;
        w_n[c * C_DIM + t] = y;            // row-major: epilogue reads rows coalesced
        float ys = 16.0f * y;
        _Float16 hi = (_Float16)ys;
        _Float16 lo = (_Float16)(ys - (float)hi);
        // frag-order store: k = t -> kt = t>>5, lane = ((t>>3)&3)*16 + (c&15), j = t&7
        const int kt = t >> 5, l = ((t >> 3) & 3) * 16 + (c & 15), j = t & 7;
        const size_t fo = ((size_t)(c >> 6) * 8 + kt) * 2048 + ((c >> 4) & 3) * 512
                        + l * 8 + j;
        wfh[fo] = hi;
        wfl[fo] = lo;
        return;
    }

    const int zb = blockIdx.x - K_CODES;   // 0..511  == g4 group index
    const int pg = zb * 64;                // global pixel base
    const int b  = pg >> 10, p0 = pg & 1023;
    const float* zp = z + (size_t)b * C_DIM * HW + p0;

    // stage 1: read [16 c x 64 p] per iter, coalesced along p; split; LDS
    const int cc = t >> 4, pp = (t & 15) * 4;
    #pragma unroll
    for (int it = 0; it < 16; it++) {
        const int c = it * 16 + cc;
        floatx4 v = *(const floatx4*)(zp + (size_t)c * HW + pp);
        #pragma unroll
        for (int j = 0; j < 4; j++) {
            float xs = 4.0f * v[j];                 // same split path as R9-R15 ->
            _Float16 h = (_Float16)xs;              // bitwise-identical operands
            _Float16 l = (_Float16)(xs - (float)h);
            pk[pp + j][c] = (unsigned)__builtin_bit_cast(unsigned short, h)
                          | ((unsigned)__builtin_bit_cast(unsigned short, l) << 16);
        }
    }
    __syncthreads();

    // stage 2: frag-order emit. t = u*64 + lane; slot (zb, kt, u) is 1 KB,
    // lane's 16B at +lane*8 halves -> fully coalesced half8 stores.
    const int u = t >> 6, l = t & 63;
    const int row = u * 16 + (l & 15);
    #pragma unroll
    for (int kt = 0; kt < 8; kt++) {
        half8 hv, lv;
        #pragma unroll
        for (int j = 0; j < 8; j++) {
            unsigned v = pk[row][kt * 32 + (l >> 4) * 8 + j];
            hv[j] = __builtin_bit_cast(_Float16, (unsigned short)(v & 0xffffu));
            lv[j] = __builtin_bit_cast(_Float16, (unsigned short)(v >> 16));
        }
        const size_t fo = ((size_t)zb * 8 + kt) * 2048 + u * 512 + l * 8;
        *(half8*)(zfh + fo) = hv;
        *(half8*)(zfl + fo) = lv;
    }
}

// ---------------- kernel 2: fused full-K GEMM + argmax + zq write -----------
// grid 512 (one 64-px group each), 256 thr = 4 waves. Wave w covers code
// group g4w = p*4+w (64 codes) in pass p (4 passes = all 1024 codes).
// Per kt: 8 B-loads (global, L2-hot), 8 A ds_reads, 48 MFMA. NO barriers.
__global__ __launch_bounds__(256, 2) void vq_gemm_fused(
        const _Float16* __restrict__ zfh, const _Float16* __restrict__ zfl,
        const _Float16* __restrict__ wfh, const _Float16* __restrict__ wfl,
        const float* __restrict__ w_n,
        float* __restrict__ zq, float* __restrict__ idx_out) {
    __shared__ float tile[64][257];          // 65.8 KB; first 64 KB doubles as A
    __shared__ float red_v[64][16];          // 4 KB   (row x (pass*4+wave))
    __shared__ int   red_i[64][16];          // 4 KB
    __shared__ int   idx_s[64];
    _Float16* Ah = (_Float16*)&tile[0][0];   // 32 KB (16384 halves)
    _Float16* Al = Ah + 16384;               // 32 KB

    const int tid  = threadIdx.x;
    const int lane = tid & 63, wave = tid >> 6;
    const int quad = lane >> 4, l15 = lane & 15;
    const int g4   = blockIdx.x;             // 64-pixel group 0..511

    // ---- stage A once: 64 chunks x 1 KB, wave w does chunks w*8..w*8+7 per plane
    {
        const _Float16* gh = zfh + (size_t)g4 * 16384 + lane * 8;
        const _Float16* gl = zfl + (size_t)g4 * 16384 + lane * 8;
        #pragma unroll
        for (int i = 0; i < 8; i++) {
            const int c = wave * 8 + i;
            GLOAD_LDS16(gh + c * 512, Ah + c * 512);
            GLOAD_LDS16(gl + c * 512, Al + c * 512);
        }
    }
    __syncthreads();                         // A staged (vmcnt drained); only barrier
                                             // before the whole K-loop
    // ---- K loop: 4 passes x 8 kt, barrier-free, waves free-run
    for (int p = 0; p < 4; p++) {
        const int g4w = p * 4 + wave;        // code group 0..15
        const int cb  = g4w * 64;            // code base
        const _Float16* pBh = wfh + (size_t)g4w * 16384 + lane * 8;
        const _Float16* pBl = wfl + (size_t)g4w * 16384 + lane * 8;

        floatx4 acc[4][4];
        #pragma unroll
        for (int i = 0; i < 4; i++)
            #pragma unroll
            for (int j = 0; j < 4; j++) acc[i][j] = (floatx4){0.f, 0.f, 0.f, 0.f};

        for (int kt = 0; kt < 8; kt++) {
            half8 bh[4], bl[4], ah[4], al[4];
            #pragma unroll
            for (int i = 0; i < 4; i++) {
                bh[i] = *(const half8*)(pBh + kt * 2048 + i * 512);
                bl[i] = *(const half8*)(pBl + kt * 2048 + i * 512);
                ah[i] = *(const half8*)&Ah[kt * 2048 + i * 512 + lane * 8];
                al[i] = *(const half8*)&Al[kt * 2048 + i * 512 + lane * 8];
            }
            __builtin_amdgcn_s_setprio(1);
            #pragma unroll
            for (int mi = 0; mi < 4; mi++)
                #pragma unroll
                for (int ni = 0; ni < 4; ni++) {
                    acc[mi][ni] = __builtin_amdgcn_mfma_f32_16x16x32_f16(ah[mi], bh[ni], acc[mi][ni], 0, 0, 0);
                    acc[mi][ni] = __builtin_amdgcn_mfma_f32_16x16x32_f16(ah[mi], bl[ni], acc[mi][ni], 0, 0, 0);
                    acc[mi][ni] = __builtin_amdgcn_mfma_f32_16x16x32_f16(al[mi], bh[ni], acc[mi][ni], 0, 0, 0);
                }
            __builtin_amdgcn_s_setprio(0);
        }

        // fold this pass's 64 codes into per-row best, park in LDS
        #pragma unroll
        for (int mi = 0; mi < 4; mi++) {
            #pragma unroll
            for (int r = 0; r < 4; r++) {
                float bv = -__builtin_inff();
                int   bi = 0x7fffffff;
                #pragma unroll
                for (int ni = 0; ni < 4; ni++) {
                    float v = acc[mi][ni][r];
                    int  ci = cb + ni * 16 + l15;
                    if (v > bv || (v == bv && ci < bi)) { bv = v; bi = ci; }
                }
                #pragma unroll
                for (int mk = 8; mk; mk >>= 1) {
                    float ov = __shfl_xor(bv, mk, 16);
                    int   oi = __shfl_xor(bi, mk, 16);
                    if (ov > bv || (ov == bv && oi < bi)) { bv = ov; bi = oi; }
                }
                if (l15 == 0) {
                    int row = mi * 16 + quad * 4 + r;   // C/D: row=(lane>>4)*4+reg
                    red_v[row][g4w] = bv;
                    red_i[row][g4w] = bi;
                }
            }
        }
    }
    __syncthreads();                         // all 16 entries parked; A dead

    // ---- final argmax over 16 entries, write indices
    if (tid < 64) {
        float bv = red_v[tid][0]; int bi = red_i[tid][0];
        #pragma unroll
        for (int e = 1; e < 16; e++) {
            float v = red_v[tid][e];
            int   c = red_i[tid][e];
            if (v > bv || (v == bv && c < bi)) { bv = v; bi = c; }
        }
        idx_s[tid] = bi;
        idx_out[g4 * 64 + tid] = (float)bi;
    }
    __syncthreads();

    // ---- gather codebook rows -> LDS tile (overlays dead A) ----------------
    #pragma unroll
    for (int i = 0; i < 16; i++) {
        const int px = wave * 16 + i;
        const int row = idx_s[px];           // wave-uniform broadcast
        floatx4 v = *(const floatx4*)(w_n + (size_t)row * C_DIM + lane * 4);
        *(floatx4*)&tile[px][lane * 4] = v;
    }
    __syncthreads();
    // ---- coalesced zq stores: float4 along pixels --------------------------
    const int n0 = g4 * 64, bb = n0 >> 10, p0 = n0 & 1023;
    float* zqb = zq + (size_t)bb * (C_DIM * HW) + p0;
    #pragma unroll
    for (int it = 0; it < 16; it++) {
        const int c = it * 16 + wave * 4 + (lane >> 4);   // 0..255
        const int px = (lane & 15) * 4;
        floatx4 v = { tile[px][c], tile[px + 1][c], tile[px + 2][c], tile[px + 3][c] };
        *(floatx4*)(zqb + (size_t)c * HW + px) = v;
    }
}

// ---------------- launcher --------------------------------------------------
extern "C" void kernel_launch(void* const* d_in, const int* in_sizes, int n_in,
                              void* d_out, int out_size, void* d_ws, size_t ws_size,
                              hipStream_t stream) {
    const float* z = (const float*)d_in[0];   // 32*256*32*32
    const float* w = (const float*)d_in[1];   // 1024*256
    float* out     = (float*)d_out;           // z_q (8388608) ++ indices (32768)

    char* ws = (char*)d_ws;                              // 34 MB used
    _Float16* zfh  = (_Float16*)(ws);                    //  0 .. 16 MB
    _Float16* zfl  = (_Float16*)(ws + (16u << 20));      // 16 .. 32 MB
    float*    w_n  = (float*)(ws + (32u << 20));         // 32 .. 33 MB
    _Float16* wfh  = (_Float16*)(ws + (33u << 20));      // 33 .. 33.5 MB
    _Float16* wfl  = (_Float16*)(ws + (33u << 20) + (1u << 19)); // 33.5 .. 34 MB

    vq_prep<<<K_CODES + NPIX / 64, 256, 0, stream>>>(z, w, w_n, wfh, wfl, zfh, zfl);
    vq_gemm_fused<<<NPIX / 64, 256, 0, stream>>>(zfh, zfl, wfh, wfl, w_n,
                                                 out, out + 8388608);
}